// Round 1
// baseline (756.049 us; speedup 1.0000x reference)
//
#include <hip/hip_runtime.h>
#include <cstddef>

#define NN 50000
#define HH 128
#define TT 4
#define EE 150000

typedef __attribute__((ext_vector_type(8))) short bfrag8;
typedef __attribute__((ext_vector_type(4))) float f32x4;
typedef __attribute__((ext_vector_type(8))) unsigned short u16x8;

__device__ __forceinline__ float sigm(float v) { return 1.0f / (1.0f + __expf(-v)); }

__device__ __forceinline__ float gru_elem(float xr, float xz, float xn,
                                          float hr, float hz, float hn, float h) {
    float r = sigm(xr + hr);
    float z = sigm(xz + hz);
    float nn = tanhf(xn + r * hn);
    return (1.f - z) * nn + z * h;
}

__device__ __forceinline__ unsigned short f2b(float f) {
    unsigned int u = __float_as_uint(f);
    u += 0x7fffu + ((u >> 16) & 1u);
    return (unsigned short)(u >> 16);
}
__device__ __forceinline__ float b2f(unsigned short s) {
    return __uint_as_float(((unsigned int)s) << 16);
}

__device__ __forceinline__ void gload_lds16(const void* gp, void* lp) {
    __builtin_amdgcn_global_load_lds(
        (const __attribute__((address_space(1))) unsigned int*)gp,
        (__attribute__((address_space(3))) unsigned int*)lp, 16, 0, 0);
}

// ================= bucket CSR build (once per call) =================
__global__ __launch_bounds__(256)
void place_bucket(const int* __restrict__ edges, int* __restrict__ cnt,
                  unsigned int* __restrict__ rows) {
    int eg = blockIdx.x * 256 + threadIdx.x;
    if (eg >= TT * EE) return;
    int t = eg / EE;
    int src = edges[eg * 2];
    int tgt = edges[eg * 2 + 1];
    int p = atomicAdd(&cnt[tgt], 1);
    if (p < 64) rows[tgt * 64 + p] = (unsigned int)src * 512u + (unsigned int)t * 128u;
}

// ================= fused setup converts =================
__device__ __forceinline__ int permrow(int f) {
    int gc = f & 127, ch = f >> 7;
    return (gc >> 4) * 48 + ch * 16 + (gc & 15);
}

__global__ __launch_bounds__(256)
void setup_convert(const float* __restrict__ msg_W,
                   const float* __restrict__ W0ih, const float* __restrict__ W0hh,
                   const float* __restrict__ W1ih, const float* __restrict__ W1hh,
                   const float* __restrict__ b0ih, const float* __restrict__ b0hh,
                   const float* __restrict__ b1ih, const float* __restrict__ b1hh,
                   const float* __restrict__ x,
                   unsigned short* __restrict__ msgWb,
                   unsigned short* __restrict__ W0ihP, unsigned short* __restrict__ W0hhP,
                   unsigned short* __restrict__ W1ihP, unsigned short* __restrict__ W1hhP,
                   float* __restrict__ biasP,
                   unsigned short* __restrict__ xb, unsigned short* __restrict__ hbA,
                   float* __restrict__ out) {
    int i = blockIdx.x * 256 + threadIdx.x;
    if (i < 131072) { msgWb[i] = f2b(msg_W[i]); return; }
    i -= 131072;
    if (i < 49152) { int f = i >> 7, k = i & 127; W0ihP[permrow(f) * 128 + k] = f2b(W0ih[i]); return; }
    i -= 49152;
    if (i < 49152) { int f = i >> 7, k = i & 127; W0hhP[permrow(f) * 128 + k] = f2b(W0hh[i]); return; }
    i -= 49152;
    if (i < 98304) { int f = i >> 8, k = i & 255; W1ihP[permrow(f) * 256 + k] = f2b(W1ih[i]); return; }
    i -= 98304;
    if (i < 49152) { int f = i >> 7, k = i & 127; W1hhP[permrow(f) * 128 + k] = f2b(W1hh[i]); return; }
    i -= 49152;
    if (i < 1536) {
        int which = i / 384, f = i - which * 384;
        const float* src = (which == 0) ? b0ih : (which == 1) ? b0hh : (which == 2) ? b1ih : b1hh;
        biasP[which * 384 + permrow(f)] = src[f];
        return;
    }
    i -= 1536;
    if (i < NN * HH) {
        float v = x[i];
        unsigned short b = f2b(v);
        xb[i] = b;
        hbA[i] = b;
        out[i] = v;
    }
}

// ================= gather: inc[n] = sum_edges Z[rows[p] + c] =================
__global__ __launch_bounds__(256)
void gather64(const int* __restrict__ cnt, const unsigned int* __restrict__ rows,
              const unsigned short* __restrict__ Z, unsigned short* __restrict__ incb) {
    int gid = blockIdx.x * 256 + threadIdx.x;
    int n = gid >> 6;
    int lane = gid & 63;
    int sub = lane >> 4;
    int c = (lane & 15) * 8;
    int m = cnt[n];
    if (m > 64) m = 64;
    const unsigned int* rp = rows + n * 64;
    float a[8] = {};
    int p = sub;
    for (; p + 4 < m; p += 8) {
        unsigned int o0 = rp[p], o1 = rp[p + 4];
        u16x8 v0 = *(const u16x8*)&Z[o0 + c];
        u16x8 v1 = *(const u16x8*)&Z[o1 + c];
        #pragma unroll
        for (int j = 0; j < 8; ++j)
            a[j] += b2f((unsigned short)v0[j]) + b2f((unsigned short)v1[j]);
    }
    for (; p < m; p += 4) {
        u16x8 v = *(const u16x8*)&Z[rp[p] + c];
        #pragma unroll
        for (int j = 0; j < 8; ++j) a[j] += b2f((unsigned short)v[j]);
    }
    #pragma unroll
    for (int j = 0; j < 8; ++j) a[j] += __shfl_xor(a[j], 16, 64);
    #pragma unroll
    for (int j = 0; j < 8; ++j) a[j] += __shfl_xor(a[j], 32, 64);
    if (sub == 0) {
        u16x8 o;
        #pragma unroll
        for (int j = 0; j < 8; ++j) o[j] = f2b(a[j]);
        *(u16x8*)&incb[(size_t)n * 128 + c] = o;
    }
}

// ================= Z GEMM (initial Z_0 only): Z = h @ msgW^T + msg_b =================
__global__ __launch_bounds__(256)
void z_gemm(const unsigned short* __restrict__ A0,
            const unsigned short* __restrict__ B,
            const float* __restrict__ bias,
            unsigned short* __restrict__ C) {
    __shared__ unsigned short lsA[128 * 64];
    __shared__ unsigned short lsB[128 * 64];
    const int tid = threadIdx.x;
    const int lane = tid & 63;
    const int w = tid >> 6;
    const int wm = w >> 1, wn = w & 1;
    const int ln15 = lane & 15;
    const int quad = lane >> 4;
    const int swz = ln15 & 7;
    const int mbase = blockIdx.x * 128;
    const int fbase = blockIdx.y * 128;
    const int qg = (lane & 7) ^ (lane >> 3);

    f32x4 acc[4][4];
    #pragma unroll
    for (int i = 0; i < 4; ++i)
        #pragma unroll
        for (int j = 0; j < 4; ++j)
            acc[i][j] = (f32x4){0.f, 0.f, 0.f, 0.f};

    #pragma unroll
    for (int tile = 0; tile < 2; ++tile) {
        const int ck0 = tile << 3;
        #pragma unroll
        for (int i = 0; i < 4; ++i) {
            const int r = i * 32 + (w << 3) + (lane >> 3);
            const int chunk = ck0 + qg;
            int grow = mbase + r;
            if (grow > NN - 1) grow = NN - 1;
            const int kel = chunk << 3;
            gload_lds16(A0 + (size_t)grow * 128 + kel, &lsA[(i * 32 + (w << 3)) * 64]);
            gload_lds16(B + (size_t)(fbase + r) * 128 + kel, &lsB[(i * 32 + (w << 3)) * 64]);
        }
        __syncthreads();
        #pragma unroll
        for (int kk = 0; kk < 2; ++kk) {
            const int cs = (((kk * 4 + quad) ^ swz)) << 3;
            bfrag8 aF[4], bF[4];
            #pragma unroll
            for (int mt = 0; mt < 4; ++mt)
                aF[mt] = *(const bfrag8*)&lsA[(wm * 64 + mt * 16 + ln15) * 64 + cs];
            #pragma unroll
            for (int nt = 0; nt < 4; ++nt)
                bF[nt] = *(const bfrag8*)&lsB[(wn * 64 + nt * 16 + ln15) * 64 + cs];
            #pragma unroll
            for (int mt = 0; mt < 4; ++mt)
                #pragma unroll
                for (int nt = 0; nt < 4; ++nt)
                    acc[mt][nt] = __builtin_amdgcn_mfma_f32_16x16x32_bf16(
                        aF[mt], bF[nt], acc[mt][nt], 0, 0, 0);
        }
        __syncthreads();
    }

    float bcol[4];
    #pragma unroll
    for (int nt = 0; nt < 4; ++nt)
        bcol[nt] = bias[fbase + wn * 64 + nt * 16 + ln15];
    #pragma unroll
    for (int mt = 0; mt < 4; ++mt) {
        #pragma unroll
        for (int reg = 0; reg < 4; ++reg) {
            const int grow = mbase + wm * 64 + mt * 16 + quad * 4 + reg;
            if (grow < NN) {
                #pragma unroll
                for (int nt = 0; nt < 4; ++nt) {
                    const int gcol = fbase + wn * 64 + nt * 16 + ln15;
                    C[(size_t)grow * 512 + gcol] = f2b(acc[mt][nt][reg] + bcol[nt]);
                }
            }
        }
    }
}

// ============ fused per-step kernel ============
// gx = [Ax|Ai] @ Wih^T (K=128 or 256), gh = h @ Whh^T (K=128), GRU gate in
// registers (no gxb round-trip), then Z_next = h_next @ msgWn^T + msgbn
// straight from the LDS h_next tile (no hbn re-read by a separate z_gemm).
// LDS map (u16 idx): AX 0..8191 | AI 8192..16383 | AH 16384..24575 |
//                    BB 24576..49151 (384x64) | HT 49152..57343 (64x128)
// Z-phase B-stage ZBUF overlays 0..32767 (A/B regions dead by then).
template<int NGX>
__global__ __launch_bounds__(512)
void fused_step(const unsigned short* __restrict__ Ax,
                const unsigned short* __restrict__ Ai,
                const unsigned short* __restrict__ Wih, int Kih,
                const unsigned short* __restrict__ Whh,
                const float* __restrict__ bih,
                const float* __restrict__ bhh,
                const unsigned short* __restrict__ hb,
                const float* __restrict__ hcur,
                float* __restrict__ hnext,
                unsigned short* __restrict__ hbn,
                const unsigned short* __restrict__ msgWn,
                const float* __restrict__ msgbn,
                unsigned short* __restrict__ Zb,
                int M) {
    __shared__ unsigned short lds[57344];
    const int OFF_AX = 0, OFF_AI = 8192, OFF_AH = 16384;
    const int OFF_BB = 24576, OFF_HT = 49152, OFF_ZB = 0;

    const int tid = threadIdx.x;
    const int lane = tid & 63;
    const int w = tid >> 6;
    const int ln15 = lane & 15;
    const int quad = lane >> 4;
    const int swz = ln15 & 7;
    const int mbase = blockIdx.x * 64;

    // ---- stage A tiles (x?, inc, h): 64x128 each, chunk-XOR pre-swizzled src ----
    #pragma unroll
    for (int i = 0; i < 2; ++i) {
        const int r0 = i * 32 + w * 4;
        const int row = r0 + (lane >> 4);
        const int pos = lane & 15;
        int grow = mbase + row;
        if (grow > M - 1) grow = M - 1;
        const int sc = (pos & 8) | ((pos & 7) ^ (row & 7));
        const size_t off = (size_t)grow * 128 + sc * 8;
        if (NGX == 4) gload_lds16(Ax + off, &lds[OFF_AX + r0 * 128]);
        gload_lds16(Ai + off, &lds[OFF_AI + r0 * 128]);
        gload_lds16(hb + off, &lds[OFF_AH + r0 * 128]);
    }

    f32x4 agx[4][3], agh[4][3];
    #pragma unroll
    for (int mt = 0; mt < 4; ++mt)
        #pragma unroll
        for (int nt = 0; nt < 3; ++nt) {
            agx[mt][nt] = (f32x4){0.f, 0.f, 0.f, 0.f};
            agh[mt][nt] = (f32x4){0.f, 0.f, 0.f, 0.f};
        }

    // ---- gx GEMM: NGX halves of 64 k-cols each ----
    #pragma unroll
    for (int hh = 0; hh < NGX; ++hh) {
        #pragma unroll
        for (int i = 0; i < 6; ++i) {
            const int r0 = i * 64 + w * 8;
            const int row = r0 + (lane >> 3);
            const int pos = lane & 7;
            const int sc = hh * 8 + (pos ^ (row & 7));
            gload_lds16(Wih + (size_t)row * Kih + sc * 8, &lds[OFF_BB + r0 * 64]);
        }
        __syncthreads();
        const int abase = (NGX == 4) ? (hh < 2 ? OFF_AX : OFF_AI) : OFF_AI;
        const int ha = (NGX == 4) ? (hh & 1) : hh;
        #pragma unroll
        for (int kk = 0; kk < 2; ++kk) {
            const int cpos = (kk * 4 + quad) ^ swz;
            bfrag8 aF[4], bF[3];
            #pragma unroll
            for (int mt = 0; mt < 4; ++mt)
                aF[mt] = *(const bfrag8*)&lds[abase + (mt * 16 + ln15) * 128 + (ha * 8 + cpos) * 8];
            #pragma unroll
            for (int nt = 0; nt < 3; ++nt)
                bF[nt] = *(const bfrag8*)&lds[OFF_BB + (w * 48 + nt * 16 + ln15) * 64 + cpos * 8];
            #pragma unroll
            for (int mt = 0; mt < 4; ++mt)
                #pragma unroll
                for (int nt = 0; nt < 3; ++nt)
                    agx[mt][nt] = __builtin_amdgcn_mfma_f32_16x16x32_bf16(
                        aF[mt], bF[nt], agx[mt][nt], 0, 0, 0);
        }
        __syncthreads();
    }

    // ---- gh GEMM: 2 halves, A = h tile, B = Whh ----
    #pragma unroll
    for (int hh = 0; hh < 2; ++hh) {
        #pragma unroll
        for (int i = 0; i < 6; ++i) {
            const int r0 = i * 64 + w * 8;
            const int row = r0 + (lane >> 3);
            const int pos = lane & 7;
            const int sc = hh * 8 + (pos ^ (row & 7));
            gload_lds16(Whh + (size_t)row * 128 + sc * 8, &lds[OFF_BB + r0 * 64]);
        }
        __syncthreads();
        #pragma unroll
        for (int kk = 0; kk < 2; ++kk) {
            const int cpos = (kk * 4 + quad) ^ swz;
            bfrag8 aF[4], bF[3];
            #pragma unroll
            for (int mt = 0; mt < 4; ++mt)
                aF[mt] = *(const bfrag8*)&lds[OFF_AH + (mt * 16 + ln15) * 128 + (hh * 8 + cpos) * 8];
            #pragma unroll
            for (int nt = 0; nt < 3; ++nt)
                bF[nt] = *(const bfrag8*)&lds[OFF_BB + (w * 48 + nt * 16 + ln15) * 64 + cpos * 8];
            #pragma unroll
            for (int mt = 0; mt < 4; ++mt)
                #pragma unroll
                for (int nt = 0; nt < 3; ++nt)
                    agh[mt][nt] = __builtin_amdgcn_mfma_f32_16x16x32_bf16(
                        aF[mt], bF[nt], agh[mt][nt], 0, 0, 0);
        }
        __syncthreads();
    }

    // ---- prefetch Z-weight half 0 into ZBUF while the gate runs (hides L2 lat) ----
    if (msgWn) {
        #pragma unroll
        for (int i = 0; i < 8; ++i) {
            const int r0 = i * 64 + w * 8;
            const int row = r0 + (lane >> 3);
            const int pos = lane & 7;
            const int sc = pos ^ (row & 7);
            gload_lds16(msgWn + (size_t)row * 128 + sc * 8, &lds[OFF_ZB + r0 * 64]);
        }
    }

    // ---- GRU gate, register-local (gx and gh share the permuted layout) ----
    const float bir = bih[w * 48 + ln15];
    const float biz = bih[w * 48 + 16 + ln15];
    const float bin = bih[w * 48 + 32 + ln15];
    const float bhr = bhh[w * 48 + ln15];
    const float bhz = bhh[w * 48 + 16 + ln15];
    const float bhn = bhh[w * 48 + 32 + ln15];
    const int gc = w * 16 + ln15;
    const int hchunk = gc >> 3;
    #pragma unroll
    for (int mt = 0; mt < 4; ++mt) {
        #pragma unroll
        for (int reg = 0; reg < 4; ++reg) {
            const int lrow = mt * 16 + quad * 4 + reg;
            const int row = mbase + lrow;
            const bool valid = (row < M);
            const float xr = agx[mt][0][reg] + bir;
            const float xz = agx[mt][1][reg] + biz;
            const float xn = agx[mt][2][reg] + bin;
            const float hr = agh[mt][0][reg] + bhr;
            const float hz = agh[mt][1][reg] + bhz;
            const float hn = agh[mt][2][reg] + bhn;
            const float h = valid ? hcur[(size_t)row * 128 + gc] : 0.f;
            const float o = gru_elem(xr, xz, xn, hr, hz, hn, h);
            const unsigned short ob = f2b(o);
            if (valid) {
                hnext[(size_t)row * 128 + gc] = o;
                hbn[(size_t)row * 128 + gc] = ob;
            }
            if (msgWn) {
                const int sp = (hchunk & 8) | ((hchunk & 7) ^ (lrow & 7));
                lds[OFF_HT + lrow * 128 + sp * 8 + (gc & 7)] = ob;
            }
        }
    }
    if (!msgWn) return;

    // ---- Z GEMM: Z = h_next(LDS) @ msgWn^T + msgbn; 8 waves x 64 cols ----
    f32x4 az[4][4];
    #pragma unroll
    for (int mt = 0; mt < 4; ++mt)
        #pragma unroll
        for (int nt = 0; nt < 4; ++nt)
            az[mt][nt] = (f32x4){0.f, 0.f, 0.f, 0.f};

    #pragma unroll
    for (int kh = 0; kh < 2; ++kh) {
        if (kh == 1) {
            __syncthreads();
            #pragma unroll
            for (int i = 0; i < 8; ++i) {
                const int r0 = i * 64 + w * 8;
                const int row = r0 + (lane >> 3);
                const int pos = lane & 7;
                const int sc = 8 + (pos ^ (row & 7));
                gload_lds16(msgWn + (size_t)row * 128 + sc * 8, &lds[OFF_ZB + r0 * 64]);
            }
        }
        __syncthreads();
        #pragma unroll
        for (int kk = 0; kk < 2; ++kk) {
            const int cpos = (kk * 4 + quad) ^ swz;
            bfrag8 aF[4], bF[4];
            #pragma unroll
            for (int mt = 0; mt < 4; ++mt)
                aF[mt] = *(const bfrag8*)&lds[OFF_HT + (mt * 16 + ln15) * 128 + (kh * 8 + cpos) * 8];
            #pragma unroll
            for (int nt = 0; nt < 4; ++nt)
                bF[nt] = *(const bfrag8*)&lds[OFF_ZB + (w * 64 + nt * 16 + ln15) * 64 + cpos * 8];
            #pragma unroll
            for (int mt = 0; mt < 4; ++mt)
                #pragma unroll
                for (int nt = 0; nt < 4; ++nt)
                    az[mt][nt] = __builtin_amdgcn_mfma_f32_16x16x32_bf16(
                        aF[mt], bF[nt], az[mt][nt], 0, 0, 0);
        }
    }

    float bz4[4];
    #pragma unroll
    for (int nt = 0; nt < 4; ++nt)
        bz4[nt] = msgbn[w * 64 + nt * 16 + ln15];
    #pragma unroll
    for (int mt = 0; mt < 4; ++mt) {
        #pragma unroll
        for (int reg = 0; reg < 4; ++reg) {
            const int grow = mbase + mt * 16 + quad * 4 + reg;
            if (grow < M) {
                #pragma unroll
                for (int nt = 0; nt < 4; ++nt)
                    Zb[(size_t)grow * 512 + w * 64 + nt * 16 + ln15] =
                        f2b(az[mt][nt][reg] + bz4[nt]);
            }
        }
    }
}

extern "C" void kernel_launch(void* const* d_in, const int* in_sizes, int n_in,
                              void* d_out, int out_size, void* d_ws, size_t ws_size,
                              hipStream_t stream) {
    (void)in_sizes; (void)n_in; (void)out_size; (void)ws_size;
    const float* x     = (const float*)d_in[0];
    const int*   edges = (const int*)d_in[1];
    const float* msg_W = (const float*)d_in[2];
    const float* msg_b = (const float*)d_in[3];
    const float* W0ih  = (const float*)d_in[4];
    const float* W0hh  = (const float*)d_in[5];
    const float* b0ih  = (const float*)d_in[6];
    const float* b0hh  = (const float*)d_in[7];
    const float* W1ih  = (const float*)d_in[8];
    const float* W1hh  = (const float*)d_in[9];
    const float* b1ih  = (const float*)d_in[10];
    const float* b1hh  = (const float*)d_in[11];
    float* out = (float*)d_out;

    // ---- workspace layout (float units) ----
    float* ws = (float*)d_ws;
    unsigned short* Zb   = (unsigned short*)ws;                  // N*512 u16
    unsigned short* incb = (unsigned short*)(ws + 22400000);     // N*128 u16
    unsigned short* xb   = (unsigned short*)(ws + 25600000);     // N*128
    unsigned short* hbA  = (unsigned short*)(ws + 28800000);
    unsigned short* hbB  = (unsigned short*)(ws + 32000000);
    float* hA            = ws + 35200000;                        // N*128 fp32
    unsigned short* wb   = (unsigned short*)(ws + 41600000);
    unsigned short* msgWb = wb;               // 131072 u16
    unsigned short* W0ihP = wb + 131072;      // 49152
    unsigned short* W0hhP = wb + 180224;      // 49152
    unsigned short* W1ihP = wb + 229376;      // 98304
    unsigned short* W1hhP = wb + 327680;      // 49152
    float* biasP        = ws + 41800000;                         // 1536 fl
    int*          cnt   = (int*)(ws + 41900000);                 // NN ints
    unsigned int* rows  = (unsigned int*)(ws + 42000000);        // NN*64 u32

    // ---- bucket CSR build ----
    hipMemsetAsync(cnt, 0, (size_t)NN * sizeof(int), stream);
    place_bucket<<<(TT * EE + 255) / 256, 256, 0, stream>>>(edges, cnt, rows);

    // ---- fused converts (also writes out = x as fp32 h0) ----
    setup_convert<<<26478, 256, 0, stream>>>(msg_W, W0ih, W0hh, W1ih, W1hh,
                                             b0ih, b0hh, b1ih, b1hh, x,
                                             msgWb, W0ihP, W0hhP, W1ihP, W1hhP,
                                             biasP, xb, hbA, out);

    const int mblocks = (NN + 127) / 128;   // 391
    const int gblocks = (NN + 63) / 64;     // 782

    // initial Z_0 = h0 @ msgW[0]^T + msg_b[0]
    z_gemm<<<dim3(mblocks, 4), 256, 0, stream>>>(hbA, msgWb, msg_b, Zb);

    for (int s = 0; s < 6; ++s) {
        const int l = s / 3;
        const int ln = (s + 1) / 3;     // layer of the NEXT step's messages
        const float* hcur  = (s % 2 == 0) ? out : hA;
        float*       hnext = (s % 2 == 0) ? hA : out;
        unsigned short* hbc = (s % 2 == 0) ? hbA : hbB;
        unsigned short* hbn = (s % 2 == 0) ? hbB : hbA;
        const unsigned short* mwn = (s < 5) ? msgWb + (size_t)ln * 65536 : nullptr;
        const float* mbn = (s < 5) ? msg_b + (size_t)ln * 512 : nullptr;

        gather64<<<(NN * 64) / 256, 256, 0, stream>>>(cnt, rows, Zb, incb);
        if (l == 0)
            fused_step<2><<<gblocks, 512, 0, stream>>>(
                incb, incb, W0ihP, 128, W0hhP, biasP, biasP + 384,
                hbc, hcur, hnext, hbn, mwn, mbn, Zb, NN);
        else
            fused_step<4><<<gblocks, 512, 0, stream>>>(
                xb, incb, W1ihP, 256, W1hhP, biasP + 768, biasP + 1152,
                hbc, hcur, hnext, hbn, mwn, mbn, Zb, NN);
    }
    // s=5 (odd) writes hnext=out — final h lands in d_out.
}

// Round 3
// 730.553 us; speedup vs baseline: 1.0349x; 1.0349x over previous
//
#include <hip/hip_runtime.h>
#include <cstddef>

#define NN 50000
#define HH 128
#define TT 4
#define EE 150000

typedef __attribute__((ext_vector_type(8))) short bfrag8;
typedef __attribute__((ext_vector_type(4))) float f32x4;
typedef __attribute__((ext_vector_type(8))) unsigned short u16x8;

__device__ __forceinline__ float sigm(float v) { return 1.0f / (1.0f + __expf(-v)); }

__device__ __forceinline__ unsigned short f2b(float f) {
    unsigned int u = __float_as_uint(f);
    u += 0x7fffu + ((u >> 16) & 1u);
    return (unsigned short)(u >> 16);
}
__device__ __forceinline__ float b2f(unsigned short s) {
    return __uint_as_float(((unsigned int)s) << 16);
}

__device__ __forceinline__ void gload_lds16(const void* gp, void* lp) {
    __builtin_amdgcn_global_load_lds(
        (const __attribute__((address_space(1))) unsigned int*)gp,
        (__attribute__((address_space(3))) unsigned int*)lp, 16, 0, 0);
}

// ================= bucket build: per-(node,t) buckets, u16 src ids =================
// deg per (n,t) ~ Poisson(3): P(>32) ~ 1e-20 -> cap 32 safe.
__global__ __launch_bounds__(256)
void place_bucket(const int* __restrict__ edges, int* __restrict__ deg,
                  unsigned short* __restrict__ rows16) {
    int eg = blockIdx.x * 256 + threadIdx.x;
    if (eg >= TT * EE) return;
    int t = eg / EE;
    int src = edges[eg * 2];
    int tgt = edges[eg * 2 + 1];
    int p = atomicAdd(&deg[tgt * 4 + t], 1);
    if (p < 32) rows16[(tgt * 4 + t) * 32 + p] = (unsigned short)src;
}

// ================= setup: weight permutes + bf16 converts =================
// Bmsg[l][f][t*128+h] = msg_W[l][t][f][h]                      (128x512 per layer)
// Wrz[l][p][k]: p = (gc>>4)*32 + g*16 + (gc&15), g in {r,z}; k<Kih from Wih, else Whh
// Wxn[l][gc][k] = Wih[256+gc][k];  Whn[l][gc][k] = Whh[256+gc][k]
// bias[l][0..256) = bih_g[gc]+bhh_g[gc] (perm-rz); [256..384)=bih_n; [384..512)=bhh_n
__global__ __launch_bounds__(256)
void setup_convert(const float* __restrict__ msg_W,
                   const float* __restrict__ W0ih, const float* __restrict__ W0hh,
                   const float* __restrict__ W1ih, const float* __restrict__ W1hh,
                   const float* __restrict__ b0ih, const float* __restrict__ b0hh,
                   const float* __restrict__ b1ih, const float* __restrict__ b1hh,
                   const float* __restrict__ x,
                   unsigned short* __restrict__ wb, float* __restrict__ biasP,
                   unsigned short* __restrict__ xb, unsigned short* __restrict__ hbA,
                   float* __restrict__ out) {
    int i = blockIdx.x * 256 + threadIdx.x;
    if (i < 131072) {   // Bmsg [2][128][512]
        int l = i >> 16, r = i & 65535;
        int f = r >> 9, k = r & 511, t = k >> 7, h = k & 127;
        wb[i] = f2b(msg_W[l * 65536 + t * 16384 + f * 128 + h]);
        return;
    }
    i -= 131072;
    if (i < 65536) {    // Wrz0 [256][256]
        int p = i >> 8, k = i & 255;
        int g = (p >> 4) & 1, gc = (p >> 5) * 16 + (p & 15);
        int f = g * 128 + gc;
        float v = (k < 128) ? W0ih[f * 128 + k] : W0hh[f * 128 + (k - 128)];
        wb[131072 + i] = f2b(v);
        return;
    }
    i -= 65536;
    if (i < 98304) {    // Wrz1 [256][384]
        int p = i / 384, k = i - p * 384;
        int g = (p >> 4) & 1, gc = (p >> 5) * 16 + (p & 15);
        int f = g * 128 + gc;
        float v = (k < 256) ? W1ih[f * 256 + k] : W1hh[f * 128 + (k - 256)];
        wb[196608 + i] = f2b(v);
        return;
    }
    i -= 98304;
    if (i < 16384) {    // Wxn0 [128][128]
        int gc = i >> 7, k = i & 127;
        wb[294912 + i] = f2b(W0ih[(256 + gc) * 128 + k]);
        return;
    }
    i -= 16384;
    if (i < 32768) {    // Wxn1 [128][256]
        int gc = i >> 8, k = i & 255;
        wb[311296 + i] = f2b(W1ih[(256 + gc) * 256 + k]);
        return;
    }
    i -= 32768;
    if (i < 16384) {    // Whn0 [128][128]
        int gc = i >> 7, k = i & 127;
        wb[344064 + i] = f2b(W0hh[(256 + gc) * 128 + k]);
        return;
    }
    i -= 16384;
    if (i < 16384) {    // Whn1 [128][128]
        int gc = i >> 7, k = i & 127;
        wb[360448 + i] = f2b(W1hh[(256 + gc) * 128 + k]);
        return;
    }
    i -= 16384;
    if (i < 1024) {     // bias [2][512]
        int l = i >> 9, r = i & 511;
        const float* bi = l ? b1ih : b0ih;
        const float* bh = l ? b1hh : b0hh;
        float v;
        if (r < 256) {
            int g = (r >> 4) & 1, gc = (r >> 5) * 16 + (r & 15);
            v = bi[g * 128 + gc] + bh[g * 128 + gc];
        } else if (r < 384) {
            v = bi[256 + (r - 256)];
        } else {
            v = bh[256 + (r - 384)];
        }
        biasP[i] = v;
        return;
    }
    i -= 1024;
    if (i < NN * HH) {
        float v = x[i];
        unsigned short b = f2b(v);
        xb[i] = b;
        hbA[i] = b;
        out[i] = v;
    }
}

// ================= fused step kernel =================
// Per 64-row block: gather S (LDS) -> inc = S @ Bm^T + deg.b (regs->LDS) ->
// rz = [x|inc|h] @ Wrz^T, xn = [x|inc] @ Wxn^T, hn = h @ Whn^T -> GRU gate.
// LDS 80KB exact: phase1 S[0..32768) Bm[32768..40960);
//                 phase2 x[0..8192) inc[8192..16384) h[16384..24576) W[24576..40960)
template<int L>
__global__ __launch_bounds__(512, 4)
void step_kernel(const int* __restrict__ deg, const unsigned short* __restrict__ rows16,
                 const unsigned short* __restrict__ hb,
                 const unsigned short* __restrict__ xb,
                 const unsigned short* __restrict__ Bm,
                 const float* __restrict__ mb,
                 const unsigned short* __restrict__ Wrz,
                 const unsigned short* __restrict__ Wxn,
                 const unsigned short* __restrict__ Whn,
                 const float* __restrict__ bias,
                 const float* __restrict__ hcur,
                 float* __restrict__ hnext,
                 unsigned short* __restrict__ hbn) {
    constexpr int Kih = L ? 256 : 128;
    constexpr int KRZ = Kih + 128;
    constexpr int NRZ = KRZ / 64;
    constexpr int NXN = Kih / 64;
    __shared__ unsigned short lds[40960];
    const int OFF_S = 0, OFF_BM = 32768;
    const int OFF_X = 0, OFF_I = 8192, OFF_H = 16384, OFF_W = 24576;

    const int tid = threadIdx.x;
    const int lane = tid & 63;
    const int w = tid >> 6;
    const int ln15 = lane & 15;
    const int quad = lane >> 4;
    const int swz = ln15 & 7;
    const int mbase = blockIdx.x * 64;

    // ---- stage Bm k-chunk 0 (in flight during gather) ----
    #pragma unroll
    for (int i = 0; i < 2; ++i) {
        const int row = i * 64 + w * 8 + (lane >> 3);
        const int pos = lane & 7;
        const int sc = pos ^ (row & 7);
        gload_lds16(Bm + (size_t)row * 512 + sc * 8, &lds[OFF_BM + (i * 512 + tid) * 8]);
    }

    // ---- gather: S[lrow][t*128+c] = sum_{src in bucket(n,t)} hb[src] ----
    {
        const int t = lane >> 4;
        const int cc = (lane & 15) * 8;
        const int kg = t * 16 + (lane & 15);
        for (int j = 0; j < 8; ++j) {
            const int lrow = w * 8 + j;
            int node = mbase + lrow;
            if (node > NN - 1) node = NN - 1;
            int m = deg[node * 4 + t];
            if (m > 32) m = 32;
            const unsigned short* rp = rows16 + (node * 4 + t) * 32;
            float a[8] = {0.f, 0.f, 0.f, 0.f, 0.f, 0.f, 0.f, 0.f};
            int p = 0;
            for (; p + 1 < m; p += 2) {
                const int s0 = rp[p], s1 = rp[p + 1];
                u16x8 v0 = *(const u16x8*)&hb[s0 * 128 + cc];
                u16x8 v1 = *(const u16x8*)&hb[s1 * 128 + cc];
                #pragma unroll
                for (int q = 0; q < 8; ++q)
                    a[q] += b2f((unsigned short)v0[q]) + b2f((unsigned short)v1[q]);
            }
            if (p < m) {
                u16x8 v = *(const u16x8*)&hb[rp[p] * 128 + cc];
                #pragma unroll
                for (int q = 0; q < 8; ++q) a[q] += b2f((unsigned short)v[q]);
            }
            const int pos = (kg & ~7) | ((kg & 7) ^ (lrow & 7));
            u16x8 o;
            #pragma unroll
            for (int q = 0; q < 8; ++q) o[q] = f2b(a[q]);
            *(u16x8*)&lds[OFF_S + lrow * 512 + pos * 8] = o;
        }
    }

    // ---- inc GEMM: 8 k-tiles of 64, single-buffered Bm chunk ----
    f32x4 ainc[4];
    #pragma unroll
    for (int mt = 0; mt < 4; ++mt) ainc[mt] = (f32x4){0.f, 0.f, 0.f, 0.f};
    for (int tile = 0; tile < 8; ++tile) {
        __syncthreads();
        const int ck0 = tile << 3;
        #pragma unroll
        for (int kk = 0; kk < 2; ++kk) {
            const int cpos = (kk * 4 + quad) ^ swz;
            bfrag8 aF[4], bF;
            #pragma unroll
            for (int mt = 0; mt < 4; ++mt)
                aF[mt] = *(const bfrag8*)&lds[OFF_S + (mt * 16 + ln15) * 512 + (ck0 + cpos) * 8];
            bF = *(const bfrag8*)&lds[OFF_BM + (w * 16 + ln15) * 64 + cpos * 8];
            #pragma unroll
            for (int mt = 0; mt < 4; ++mt)
                ainc[mt] = __builtin_amdgcn_mfma_f32_16x16x32_bf16(aF[mt], bF, ainc[mt], 0, 0, 0);
        }
        __syncthreads();
        if (tile < 7) {
            #pragma unroll
            for (int i = 0; i < 2; ++i) {
                const int row = i * 64 + w * 8 + (lane >> 3);
                const int pos = lane & 7;
                const int sc = (tile + 1) * 8 + (pos ^ (row & 7));
                gload_lds16(Bm + (size_t)row * 512 + sc * 8, &lds[OFF_BM + (i * 512 + tid) * 8]);
            }
        }
    }

    // ---- stage x (L==1) and h tiles (S region now dead) ----
    #pragma unroll
    for (int i = 0; i < 2; ++i) {
        const int r0 = i * 32 + w * 4;
        const int row = r0 + (lane >> 4);
        const int pos = lane & 15;
        int grow = mbase + row;
        if (grow > NN - 1) grow = NN - 1;
        const int sc = (pos & 8) | ((pos & 7) ^ (row & 7));
        const size_t off = (size_t)grow * 128 + sc * 8;
        if (L == 1) gload_lds16(xb + off, &lds[OFF_X + r0 * 128]);
        gload_lds16(hb + off, &lds[OFF_H + r0 * 128]);
    }

    // ---- inc epilogue: + deg·msg_b, write bf16 to LDS inc tile (swizzled) ----
    {
        const int gc = w * 16 + ln15;
        const float bt0 = mb[gc], bt1 = mb[128 + gc], bt2 = mb[256 + gc], bt3 = mb[384 + gc];
        const int chunk = gc >> 3;
        const int sub = gc & 7;
        #pragma unroll
        for (int mt = 0; mt < 4; ++mt) {
            #pragma unroll
            for (int reg = 0; reg < 4; ++reg) {
                const int lrow = mt * 16 + quad * 4 + reg;
                int row = mbase + lrow;
                if (row > NN - 1) row = NN - 1;
                const int4 d4 = *(const int4*)&deg[row * 4];
                const float v = ainc[mt][reg] + d4.x * bt0 + d4.y * bt1 + d4.z * bt2 + d4.w * bt3;
                const int pos = (chunk & 8) | ((chunk & 7) ^ (lrow & 7));
                lds[OFF_I + lrow * 128 + pos * 8 + sub] = f2b(v);
            }
        }
    }

    // ---- rz / xn / hn GEMMs ----
    f32x4 arz[4][2], axn[4], ahn[4];
    #pragma unroll
    for (int mt = 0; mt < 4; ++mt) {
        arz[mt][0] = (f32x4){0.f, 0.f, 0.f, 0.f};
        arz[mt][1] = (f32x4){0.f, 0.f, 0.f, 0.f};
        axn[mt] = (f32x4){0.f, 0.f, 0.f, 0.f};
        ahn[mt] = (f32x4){0.f, 0.f, 0.f, 0.f};
    }

    for (int hh = 0; hh < NRZ; ++hh) {
        #pragma unroll
        for (int i = 0; i < 4; ++i) {
            const int row = i * 64 + w * 8 + (lane >> 3);
            const int pos = lane & 7;
            const int sc = hh * 8 + (pos ^ (row & 7));
            gload_lds16(Wrz + (size_t)row * KRZ + sc * 8, &lds[OFF_W + (i * 512 + tid) * 8]);
        }
        __syncthreads();
        const int abase = (L == 1) ? (hh < 2 ? OFF_X : hh < 4 ? OFF_I : OFF_H)
                                   : (hh < 2 ? OFF_I : OFF_H);
        const int ha = hh & 1;
        #pragma unroll
        for (int kk = 0; kk < 2; ++kk) {
            const int cpos = (kk * 4 + quad) ^ swz;
            bfrag8 aF[4], bF[2];
            #pragma unroll
            for (int mt = 0; mt < 4; ++mt)
                aF[mt] = *(const bfrag8*)&lds[abase + (mt * 16 + ln15) * 128 + (ha * 8 + cpos) * 8];
            #pragma unroll
            for (int nt = 0; nt < 2; ++nt)
                bF[nt] = *(const bfrag8*)&lds[OFF_W + (w * 32 + nt * 16 + ln15) * 64 + cpos * 8];
            #pragma unroll
            for (int mt = 0; mt < 4; ++mt)
                #pragma unroll
                for (int nt = 0; nt < 2; ++nt)
                    arz[mt][nt] = __builtin_amdgcn_mfma_f32_16x16x32_bf16(
                        aF[mt], bF[nt], arz[mt][nt], 0, 0, 0);
        }
        __syncthreads();
    }

    for (int hh = 0; hh < NXN; ++hh) {
        #pragma unroll
        for (int i = 0; i < 2; ++i) {
            const int row = i * 64 + w * 8 + (lane >> 3);
            const int pos = lane & 7;
            const int sc = hh * 8 + (pos ^ (row & 7));
            gload_lds16(Wxn + (size_t)row * Kih + sc * 8, &lds[OFF_W + (i * 512 + tid) * 8]);
        }
        __syncthreads();
        const int abase = (L == 1) ? (hh < 2 ? OFF_X : OFF_I) : OFF_I;
        const int ha = hh & 1;
        #pragma unroll
        for (int kk = 0; kk < 2; ++kk) {
            const int cpos = (kk * 4 + quad) ^ swz;
            bfrag8 aF[4], bF;
            #pragma unroll
            for (int mt = 0; mt < 4; ++mt)
                aF[mt] = *(const bfrag8*)&lds[abase + (mt * 16 + ln15) * 128 + (ha * 8 + cpos) * 8];
            bF = *(const bfrag8*)&lds[OFF_W + (w * 16 + ln15) * 64 + cpos * 8];
            #pragma unroll
            for (int mt = 0; mt < 4; ++mt)
                axn[mt] = __builtin_amdgcn_mfma_f32_16x16x32_bf16(aF[mt], bF, axn[mt], 0, 0, 0);
        }
        __syncthreads();
    }

    for (int hh = 0; hh < 2; ++hh) {
        #pragma unroll
        for (int i = 0; i < 2; ++i) {
            const int row = i * 64 + w * 8 + (lane >> 3);
            const int pos = lane & 7;
            const int sc = hh * 8 + (pos ^ (row & 7));
            gload_lds16(Whn + (size_t)row * 128 + sc * 8, &lds[OFF_W + (i * 512 + tid) * 8]);
        }
        __syncthreads();
        #pragma unroll
        for (int kk = 0; kk < 2; ++kk) {
            const int cpos = (kk * 4 + quad) ^ swz;
            bfrag8 aF[4], bF;
            #pragma unroll
            for (int mt = 0; mt < 4; ++mt)
                aF[mt] = *(const bfrag8*)&lds[OFF_H + (mt * 16 + ln15) * 128 + (hh * 8 + cpos) * 8];
            bF = *(const bfrag8*)&lds[OFF_W + (w * 16 + ln15) * 64 + cpos * 8];
            #pragma unroll
            for (int mt = 0; mt < 4; ++mt)
                ahn[mt] = __builtin_amdgcn_mfma_f32_16x16x32_bf16(aF[mt], bF, ahn[mt], 0, 0, 0);
        }
        __syncthreads();
    }

    // ---- GRU gate ----
    {
        const int gc = w * 16 + ln15;
        const float brzr = bias[w * 32 + ln15];
        const float brzz = bias[w * 32 + 16 + ln15];
        const float bxnv = bias[256 + gc];
        const float bhnv = bias[384 + gc];
        #pragma unroll
        for (int mt = 0; mt < 4; ++mt) {
            #pragma unroll
            for (int reg = 0; reg < 4; ++reg) {
                const int row = mbase + mt * 16 + quad * 4 + reg;
                if (row < NN) {
                    const float r = sigm(arz[mt][0][reg] + brzr);
                    const float z = sigm(arz[mt][1][reg] + brzz);
                    const float n = tanhf(axn[mt][reg] + bxnv + r * (ahn[mt][reg] + bhnv));
                    const float h = hcur[(size_t)row * 128 + gc];
                    const float o = (1.f - z) * n + z * h;
                    hnext[(size_t)row * 128 + gc] = o;
                    hbn[(size_t)row * 128 + gc] = f2b(o);
                }
            }
        }
    }
}

extern "C" void kernel_launch(void* const* d_in, const int* in_sizes, int n_in,
                              void* d_out, int out_size, void* d_ws, size_t ws_size,
                              hipStream_t stream) {
    (void)in_sizes; (void)n_in; (void)out_size; (void)ws_size;
    const float* x     = (const float*)d_in[0];
    const int*   edges = (const int*)d_in[1];
    const float* msg_W = (const float*)d_in[2];
    const float* msg_b = (const float*)d_in[3];
    const float* W0ih  = (const float*)d_in[4];
    const float* W0hh  = (const float*)d_in[5];
    const float* b0ih  = (const float*)d_in[6];
    const float* b0hh  = (const float*)d_in[7];
    const float* W1ih  = (const float*)d_in[8];
    const float* W1hh  = (const float*)d_in[9];
    const float* b1ih  = (const float*)d_in[10];
    const float* b1hh  = (const float*)d_in[11];
    float* out = (float*)d_out;

    // ---- workspace layout (float units) ----
    float* ws = (float*)d_ws;
    unsigned short* xb  = (unsigned short*)ws;                   // N*128 u16 -> 3.2M fl
    unsigned short* hbA = (unsigned short*)(ws + 3200000);
    unsigned short* hbB = (unsigned short*)(ws + 6400000);
    float* hA           = ws + 9600000;                          // N*128 fp32 -> 6.4M fl
    unsigned short* wb  = (unsigned short*)(ws + 16000000);      // 376832 u16
    float* biasP        = ws + 16200000;                         // 1024 fl
    int* deg            = (int*)(ws + 16300000);                 // N*4 ints = 200000 fl
    unsigned short* rows16 = (unsigned short*)(ws + 16600000);   // N*4*32 u16 = 3.2M fl

    unsigned short* Bmsg = wb;
    unsigned short* Wrz0 = wb + 131072;
    unsigned short* Wrz1 = wb + 196608;
    unsigned short* Wxn0 = wb + 294912;
    unsigned short* Wxn1 = wb + 311296;
    unsigned short* Whn0 = wb + 344064;
    unsigned short* Whn1 = wb + 360448;

    hipMemsetAsync(deg, 0, (size_t)NN * 4 * sizeof(int), stream);
    place_bucket<<<(TT * EE + 255) / 256, 256, 0, stream>>>(edges, deg, rows16);

    setup_convert<<<26476, 256, 0, stream>>>(msg_W, W0ih, W0hh, W1ih, W1hh,
                                             b0ih, b0hh, b1ih, b1hh, x,
                                             wb, biasP, xb, hbA, out);

    const int gblocks = (NN + 63) / 64;   // 782
    for (int s = 0; s < 6; ++s) {
        const int l = s / 3;
        const float* hcur  = (s % 2 == 0) ? out : hA;
        float*       hnext = (s % 2 == 0) ? hA : out;
        unsigned short* hbc = (s % 2 == 0) ? hbA : hbB;
        unsigned short* hbn = (s % 2 == 0) ? hbB : hbA;
        if (l == 0)
            step_kernel<0><<<gblocks, 512, 0, stream>>>(
                deg, rows16, hbc, xb, Bmsg, msg_b, Wrz0, Wxn0, Whn0,
                biasP, hcur, hnext, hbn);
        else
            step_kernel<1><<<gblocks, 512, 0, stream>>>(
                deg, rows16, hbc, xb, Bmsg + 65536, msg_b + 512, Wrz1, Wxn1, Whn1,
                biasP + 512, hcur, hnext, hbn);
    }
    // s=5 (odd) writes hnext=out — final h lands in d_out.
}

// Round 5
// 617.186 us; speedup vs baseline: 1.2250x; 1.1837x over previous
//
#include <hip/hip_runtime.h>
#include <cstddef>

#define NN 50000
#define HH 128
#define TT 4
#define EE 150000

typedef __attribute__((ext_vector_type(8))) short bfrag8;
typedef __attribute__((ext_vector_type(4))) float f32x4;
typedef __attribute__((ext_vector_type(8))) unsigned short u16x8;

__device__ __forceinline__ float sigm(float v) { return 1.0f / (1.0f + __expf(-v)); }

__device__ __forceinline__ unsigned short f2b(float f) {
    unsigned int u = __float_as_uint(f);
    u += 0x7fffu + ((u >> 16) & 1u);
    return (unsigned short)(u >> 16);
}
__device__ __forceinline__ float b2f(unsigned short s) {
    return __uint_as_float(((unsigned int)s) << 16);
}

__device__ __forceinline__ void gload_lds16(const void* gp, void* lp) {
    __builtin_amdgcn_global_load_lds(
        (const __attribute__((address_space(1))) unsigned int*)gp,
        (__attribute__((address_space(3))) unsigned int*)lp, 16, 0, 0);
}

// generic 128-row x 64-k weight tile stage (16KB), chunk-XOR swizzled source
__device__ __forceinline__ void stage_w(const unsigned short* __restrict__ W, int K,
                                        int rowoff, int g8, unsigned short* ldsbase,
                                        int tid, int w, int lane) {
    #pragma unroll
    for (int i = 0; i < 2; ++i) {
        const int r = i * 64 + w * 8 + (lane >> 3);
        const int sc = g8 * 8 + ((lane & 7) ^ (r & 7));
        gload_lds16(W + (size_t)(rowoff + r) * K + sc * 8, ldsbase + (i * 512 + tid) * 8);
    }
}

// ================= bucket build: t-major per-(t,node) buckets =================
// deg per (n,t) ~ Poisson(3): P(>32) ~ 1e-20 -> cap 32.
__global__ __launch_bounds__(256)
void place_bucket(const int* __restrict__ edges, int* __restrict__ degT,
                  unsigned short* __restrict__ rowsT) {
    int eg = blockIdx.x * 256 + threadIdx.x;
    if (eg >= TT * EE) return;
    int t = eg / EE;
    int src = edges[eg * 2];
    int tgt = edges[eg * 2 + 1];
    int p = atomicAdd(&degT[t * NN + tgt], 1);
    if (p < 32) rowsT[((size_t)t * NN + tgt) * 32 + p] = (unsigned short)src;
}

// ================= setup: degP pack + weight permutes + bf16 converts =================
// Bmsg[l][f][t*128+h] = msg_W[l][t][f][h]            (128x512 per layer)
// Wrz[l][p][k]: p<128 -> r-row gc=p, p>=128 -> z-row gc=p-128; k<Kih from Wih else Whh
// Wxn[l][gc][k] = Wih[256+gc][k]; Whn[l][gc][k] = Whh[256+gc][k]
// bias[l]: [0..128) r (bih+bhh), [128..256) z, [256..384) bih_n, [384..512) bhh_n
__global__ __launch_bounds__(256)
void setup_convert(const float* __restrict__ msg_W,
                   const float* __restrict__ W0ih, const float* __restrict__ W0hh,
                   const float* __restrict__ W1ih, const float* __restrict__ W1hh,
                   const float* __restrict__ b0ih, const float* __restrict__ b0hh,
                   const float* __restrict__ b1ih, const float* __restrict__ b1hh,
                   const float* __restrict__ x, const int* __restrict__ degT,
                   unsigned int* __restrict__ degP,
                   unsigned short* __restrict__ wb, float* __restrict__ biasP,
                   unsigned short* __restrict__ xb, unsigned short* __restrict__ hbA,
                   unsigned short* __restrict__ hbB, float* __restrict__ out) {
    int i = blockIdx.x * 256 + threadIdx.x;
    if (i < NN) {
        unsigned int v0 = degT[i];            if (v0 > 32) v0 = 32;
        unsigned int v1 = degT[NN + i];       if (v1 > 32) v1 = 32;
        unsigned int v2 = degT[2 * NN + i];   if (v2 > 32) v2 = 32;
        unsigned int v3 = degT[3 * NN + i];   if (v3 > 32) v3 = 32;
        degP[i] = v0 | (v1 << 8) | (v2 << 16) | (v3 << 24);
        return;
    }
    i -= NN;
    if (i < 131072) {   // Bmsg [2][128][512]
        int l = i >> 16, r = i & 65535;
        int f = r >> 9, k = r & 511, t = k >> 7, h = k & 127;
        wb[i] = f2b(msg_W[l * 65536 + t * 16384 + f * 128 + h]);
        return;
    }
    i -= 131072;
    if (i < 65536) {    // Wrz0 [256][256]
        int p = i >> 8, k = i & 255;
        int g = p >> 7, gc = p & 127;
        int f = g * 128 + gc;
        float v = (k < 128) ? W0ih[f * 128 + k] : W0hh[f * 128 + (k - 128)];
        wb[131072 + i] = f2b(v);
        return;
    }
    i -= 65536;
    if (i < 98304) {    // Wrz1 [256][384]
        int p = i / 384, k = i - p * 384;
        int g = p >> 7, gc = p & 127;
        int f = g * 128 + gc;
        float v = (k < 256) ? W1ih[f * 256 + k] : W1hh[f * 128 + (k - 256)];
        wb[196608 + i] = f2b(v);
        return;
    }
    i -= 98304;
    if (i < 16384) {    // Wxn0 [128][128]
        int gc = i >> 7, k = i & 127;
        wb[294912 + i] = f2b(W0ih[(256 + gc) * 128 + k]);
        return;
    }
    i -= 16384;
    if (i < 32768) {    // Wxn1 [128][256]
        int gc = i >> 8, k = i & 255;
        wb[311296 + i] = f2b(W1ih[(256 + gc) * 256 + k]);
        return;
    }
    i -= 32768;
    if (i < 16384) {    // Whn0 [128][128]
        int gc = i >> 7, k = i & 127;
        wb[344064 + i] = f2b(W0hh[(256 + gc) * 128 + k]);
        return;
    }
    i -= 16384;
    if (i < 16384) {    // Whn1 [128][128]
        int gc = i >> 7, k = i & 127;
        wb[360448 + i] = f2b(W1hh[(256 + gc) * 128 + k]);
        return;
    }
    i -= 16384;
    if (i < 1024) {     // bias [2][512]
        int l = i >> 9, r = i & 511;
        const float* bi = l ? b1ih : b0ih;
        const float* bh = l ? b1hh : b0hh;
        float v;
        if (r < 256) {
            int g = r >> 7, gc = r & 127;
            v = bi[g * 128 + gc] + bh[g * 128 + gc];
        } else if (r < 384) {
            v = bi[256 + (r - 256)];
        } else {
            v = bh[256 + (r - 384)];
        }
        biasP[i] = v;
        return;
    }
    i -= 1024;
    if (i < NN * HH) {
        float v = x[i];
        unsigned short b = f2b(v);
        xb[i] = b;
        hbA[i] = b;
        out[i] = v;
        return;
    }
    i -= NN * HH;
    if (i < 128) {      // zero row NN of hbA/hbB (gather's masked-lane target)
        hbA[(size_t)NN * 128 + i] = 0;
        hbB[(size_t)NN * 128 + i] = 0;
    }
}

// ================= fused step kernel (64KB LDS -> 2 blocks/CU) =================
// phase1: S[64][256]@0 (32KB) | BmA@16384 | BmB@24576 (8KB each, dbuf)
// phaseC L0: I@0 H@8192 WA@16384 WB@24576 (W dbuf, 1 barrier/tile)
// phaseC L1: X@0 I@8192 H@16384 W@24576 (single, 2 barriers/tile)
template<int L>
__global__ __launch_bounds__(512, 4)
void step_kernel(const unsigned int* __restrict__ degP,
                 const unsigned short* __restrict__ rowsT,
                 const unsigned short* __restrict__ hb,
                 const unsigned short* __restrict__ xb,
                 const unsigned short* __restrict__ Bm,
                 const float* __restrict__ mb,
                 const unsigned short* __restrict__ Wrz,
                 const unsigned short* __restrict__ Wxn,
                 const unsigned short* __restrict__ Whn,
                 const float* __restrict__ bias,
                 const float* __restrict__ hcur,
                 float* __restrict__ hnext,
                 unsigned short* __restrict__ hbn) {
    constexpr int Kih = L ? 256 : 128;
    constexpr int KRZ = Kih + 128;
    constexpr int NRZ = KRZ / 64;       // 4 or 6
    constexpr int NXN = Kih / 64;       // 2 or 4
    constexpr int NT  = 2 * NRZ + NXN + 2;  // 12 or 18
    __shared__ unsigned short lds[32768];
    constexpr int OFF_S = 0, OFF_BMA = 16384, OFF_BMB = 24576;
    constexpr int OFF_X = 0;
    constexpr int OFF_I = L ? 8192 : 0;
    constexpr int OFF_H = L ? 16384 : 8192;
    constexpr int OFF_WA = L ? 24576 : 16384;
    constexpr int OFF_WB = 24576;

    const int tid = threadIdx.x;
    const int lane = tid & 63;
    const int w = tid >> 6;
    const int ln15 = lane & 15;
    const int quad = lane >> 4;
    const int swz = ln15 & 7;
    const int mbase = blockIdx.x * 64;

    // ---- gather one t-pair into S: fixed-trip-8, predicated via zero-row NN ----
    auto do_gather = [&](int ta) {
        const int tsub = lane >> 5;         // 0/1 within pair
        const int t = ta + tsub;
        const int jh = (lane >> 4) & 1;     // node-half
        const int cl = lane & 15;
        const int cc = cl * 8;
        int node0 = mbase + w * 8 + jh * 4;
        if (node0 > NN - 4) node0 = NN - 4;
        const uint4 dp4 = *(const uint4*)&degP[node0];
        const int tsh = t * 8;
        const size_t rbase = ((size_t)t * NN + node0) * 32;
        const u16x8 ix0 = *(const u16x8*)&rowsT[rbase];
        const u16x8 ix1 = *(const u16x8*)&rowsT[rbase + 32];
        const u16x8 ix2 = *(const u16x8*)&rowsT[rbase + 64];
        const u16x8 ix3 = *(const u16x8*)&rowsT[rbase + 96];
        #pragma unroll
        for (int jj = 0; jj < 4; ++jj) {
            const unsigned int dpw = (jj == 0) ? dp4.x : (jj == 1) ? dp4.y : (jj == 2) ? dp4.z : dp4.w;
            const int m = (int)((dpw >> tsh) & 255u);
            const u16x8 ix = (jj == 0) ? ix0 : (jj == 1) ? ix1 : (jj == 2) ? ix2 : ix3;
            float a[8] = {0.f, 0.f, 0.f, 0.f, 0.f, 0.f, 0.f, 0.f};
            #pragma unroll
            for (int q = 0; q < 8; ++q) {
                unsigned int rowi = (unsigned short)ix[q];
                if (q >= m) rowi = NN;      // zeroed row
                const u16x8 v = *(const u16x8*)&hb[(size_t)rowi * 128 + cc];
                #pragma unroll
                for (int e = 0; e < 8; ++e) a[e] += b2f((unsigned short)v[e]);
            }
            if (m > 8) {                    // rare (P ~ 0.4%)
                const unsigned short* rp = &rowsT[rbase + jj * 32];
                for (int p = 8; p < m; ++p) {
                    const u16x8 v = *(const u16x8*)&hb[(size_t)rp[p] * 128 + cc];
                    #pragma unroll
                    for (int e = 0; e < 8; ++e) a[e] += b2f((unsigned short)v[e]);
                }
            }
            const int lrow = w * 8 + jh * 4 + jj;
            const int kg = tsub * 16 + cl;
            const int pos = (kg & ~7) | ((kg & 7) ^ (lrow & 7));
            u16x8 o;
            #pragma unroll
            for (int e = 0; e < 8; ++e) o[e] = f2b(a[e]);
            *(u16x8*)&lds[OFF_S + lrow * 256 + pos * 8] = o;
        }
    };

    f32x4 ainc[4];
    #pragma unroll
    for (int mt = 0; mt < 4; ++mt) ainc[mt] = (f32x4){0.f, 0.f, 0.f, 0.f};

    // ---- inc GEMM: 2 passes x 4 tiles, Bm double-buffered, 1 barrier/tile ----
    stage_w(Bm, 512, 0, 0, &lds[OFF_BMA], tid, w, lane);
    #pragma unroll
    for (int P = 0; P < 2; ++P) {
        do_gather(P * 2);
        __syncthreads();
        #pragma unroll
        for (int tt2 = 0; tt2 < 4; ++tt2) {
            const int tix = P * 4 + tt2;
            if (tix < 7)
                stage_w(Bm, 512, 0, tix + 1,
                        &lds[((tix + 1) & 1) ? OFF_BMB : OFF_BMA], tid, w, lane);
            const int bmoff = (tix & 1) ? OFF_BMB : OFF_BMA;
            #pragma unroll
            for (int kk = 0; kk < 2; ++kk) {
                const int cpos = (kk * 4 + quad) ^ swz;
                bfrag8 aFv[4];
                #pragma unroll
                for (int mt = 0; mt < 4; ++mt)
                    aFv[mt] = *(const bfrag8*)&lds[OFF_S + (mt * 16 + ln15) * 256 + (tt2 * 8 + cpos) * 8];
                const bfrag8 bFv = *(const bfrag8*)&lds[bmoff + ((w * 16 + ln15) * 8 + cpos) * 8];
                #pragma unroll
                for (int mt = 0; mt < 4; ++mt)
                    ainc[mt] = __builtin_amdgcn_mfma_f32_16x16x32_bf16(aFv[mt], bFv, ainc[mt], 0, 0, 0);
            }
            __syncthreads();
        }
    }

    // ---- phase-C entry: stage x/h + W tile0, inc epilogue -> LDS inc tile ----
    #pragma unroll
    for (int i = 0; i < 2; ++i) {
        const int r0 = i * 32 + w * 4;
        const int row = r0 + (lane >> 4);
        const int pos = lane & 15;
        int grow = mbase + row;
        if (grow > NN - 1) grow = NN - 1;
        const int sc = (pos & 8) | ((pos & 7) ^ (row & 7));
        const size_t off = (size_t)grow * 128 + sc * 8;
        if (L == 1) gload_lds16(xb + off, &lds[OFF_X + r0 * 128]);
        gload_lds16(hb + off, &lds[OFF_H + r0 * 128]);
    }
    stage_w(Wrz, KRZ, 0, 0, &lds[OFF_WA], tid, w, lane);
    {
        const int gc = w * 16 + ln15;
        const float bt0 = mb[gc], bt1 = mb[128 + gc], bt2 = mb[256 + gc], bt3 = mb[384 + gc];
        const int chunk = gc >> 3;
        const int sub = gc & 7;
        #pragma unroll
        for (int mt = 0; mt < 4; ++mt) {
            #pragma unroll
            for (int reg = 0; reg < 4; ++reg) {
                const int lrow = mt * 16 + quad * 4 + reg;
                int row = mbase + lrow;
                if (row > NN - 1) row = NN - 1;
                const unsigned int dp = degP[row];
                const float v = ainc[mt][reg]
                    + (float)(dp & 255u) * bt0 + (float)((dp >> 8) & 255u) * bt1
                    + (float)((dp >> 16) & 255u) * bt2 + (float)((dp >> 24) & 255u) * bt3;
                const int pos = (chunk & 8) | ((chunk & 7) ^ (lrow & 7));
                lds[OFF_I + lrow * 128 + pos * 8 + sub] = f2b(v);
            }
        }
    }
    __syncthreads();

    // ---- rz / xn / hn GEMM chain ----
    f32x4 arz0[4], arz1[4], axn[4], ahn[4];
    #pragma unroll
    for (int mt = 0; mt < 4; ++mt) {
        arz0[mt] = (f32x4){0.f, 0.f, 0.f, 0.f};
        arz1[mt] = (f32x4){0.f, 0.f, 0.f, 0.f};
        axn[mt] = (f32x4){0.f, 0.f, 0.f, 0.f};
        ahn[mt] = (f32x4){0.f, 0.f, 0.f, 0.f};
    }

    auto stage_T = [&](int T, int woff) {
        if (L == 0) {
            if (T < 8)       stage_w(Wrz, KRZ, (T >> 2) * 128, T & 3, &lds[woff], tid, w, lane);
            else if (T < 10) stage_w(Wxn, Kih, 0, T - 8, &lds[woff], tid, w, lane);
            else             stage_w(Whn, 128, 0, T - 10, &lds[woff], tid, w, lane);
        } else {
            if (T < 12)      stage_w(Wrz, KRZ, (T / 6) * 128, T % 6, &lds[woff], tid, w, lane);
            else if (T < 16) stage_w(Wxn, Kih, 0, T - 12, &lds[woff], tid, w, lane);
            else             stage_w(Whn, 128, 0, T - 16, &lds[woff], tid, w, lane);
        }
    };
    auto mfma_T = [&](int T, int woff) {
        int abase, ha;
        f32x4* acc;
        if (L == 0) {
            if (T < 8)       { const int hh = T & 3; abase = hh < 2 ? OFF_I : OFF_H; ha = hh & 1; acc = (T >> 2) ? arz1 : arz0; }
            else if (T < 10) { abase = OFF_I; ha = T - 8; acc = axn; }
            else             { abase = OFF_H; ha = T - 10; acc = ahn; }
        } else {
            if (T < 12)      { const int hh = T % 6; abase = hh < 2 ? OFF_X : (hh < 4 ? OFF_I : OFF_H); ha = hh & 1; acc = (T / 6) ? arz1 : arz0; }
            else if (T < 16) { const int hh = T - 12; abase = hh < 2 ? OFF_X : OFF_I; ha = hh & 1; acc = axn; }
            else             { abase = OFF_H; ha = T - 16; acc = ahn; }
        }
        #pragma unroll
        for (int kk = 0; kk < 2; ++kk) {
            const int cpos = (kk * 4 + quad) ^ swz;
            bfrag8 aFv[4];
            #pragma unroll
            for (int mt = 0; mt < 4; ++mt)
                aFv[mt] = *(const bfrag8*)&lds[abase + (mt * 16 + ln15) * 128 + (ha * 8 + cpos) * 8];
            const bfrag8 bFv = *(const bfrag8*)&lds[woff + ((w * 16 + ln15) * 8 + cpos) * 8];
            #pragma unroll
            for (int mt = 0; mt < 4; ++mt)
                acc[mt] = __builtin_amdgcn_mfma_f32_16x16x32_bf16(aFv[mt], bFv, acc[mt], 0, 0, 0);
        }
    };

    if (L == 0) {
        #pragma unroll
        for (int T = 0; T < NT; ++T) {
            if (T + 1 < NT) stage_T(T + 1, ((T + 1) & 1) ? OFF_WB : OFF_WA);
            mfma_T(T, (T & 1) ? OFF_WB : OFF_WA);
            __syncthreads();
        }
    } else {
        #pragma unroll
        for (int T = 0; T < NT; ++T) {
            mfma_T(T, OFF_WB);
            if (T + 1 < NT) {
                __syncthreads();
                stage_T(T + 1, OFF_WB);
                __syncthreads();
            }
        }
    }

    // ---- GRU gate ----
    {
        const int gc = w * 16 + ln15;
        const float br = bias[gc];
        const float bz = bias[128 + gc];
        const float bxnv = bias[256 + gc];
        const float bhnv = bias[384 + gc];
        #pragma unroll
        for (int mt = 0; mt < 4; ++mt) {
            #pragma unroll
            for (int reg = 0; reg < 4; ++reg) {
                const int row = mbase + mt * 16 + quad * 4 + reg;
                if (row < NN) {
                    const float r = sigm(arz0[mt][reg] + br);
                    const float z = sigm(arz1[mt][reg] + bz);
                    const float n = tanhf(axn[mt][reg] + bxnv + r * (ahn[mt][reg] + bhnv));
                    const float h = hcur[(size_t)row * 128 + gc];
                    const float o = (1.f - z) * n + z * h;
                    hnext[(size_t)row * 128 + gc] = o;
                    if (hbn) hbn[(size_t)row * 128 + gc] = f2b(o);
                }
            }
        }
    }
}

extern "C" void kernel_launch(void* const* d_in, const int* in_sizes, int n_in,
                              void* d_out, int out_size, void* d_ws, size_t ws_size,
                              hipStream_t stream) {
    (void)in_sizes; (void)n_in; (void)out_size; (void)ws_size;
    const float* x     = (const float*)d_in[0];
    const int*   edges = (const int*)d_in[1];
    const float* msg_W = (const float*)d_in[2];
    const float* msg_b = (const float*)d_in[3];
    const float* W0ih  = (const float*)d_in[4];
    const float* W0hh  = (const float*)d_in[5];
    const float* b0ih  = (const float*)d_in[6];
    const float* b0hh  = (const float*)d_in[7];
    const float* W1ih  = (const float*)d_in[8];
    const float* W1hh  = (const float*)d_in[9];
    const float* b1ih  = (const float*)d_in[10];
    const float* b1hh  = (const float*)d_in[11];
    float* out = (float*)d_out;

    // ---- workspace layout (float units) ----
    float* ws = (float*)d_ws;
    unsigned short* xb  = (unsigned short*)ws;                    // N*128 u16
    unsigned short* hbA = (unsigned short*)(ws + 3200000);        // (N+1)*128 u16
    unsigned short* hbB = (unsigned short*)(ws + 6400100);
    float* hA           = ws + 9700000;                           // N*128 fp32
    unsigned short* wb  = (unsigned short*)(ws + 16200000);       // 376832 u16
    float* biasP        = ws + 16400000;                          // 1024 fl
    int* degT           = (int*)(ws + 16500000);                  // 4N ints
    unsigned int* degP  = (unsigned int*)(ws + 16750000);         // N u32
    unsigned short* rowsT = (unsigned short*)(ws + 16850000);     // 4N*32 u16

    unsigned short* Bmsg = wb;
    unsigned short* Wrz0 = wb + 131072;
    unsigned short* Wrz1 = wb + 196608;
    unsigned short* Wxn0 = wb + 294912;
    unsigned short* Wxn1 = wb + 311296;
    unsigned short* Whn0 = wb + 344064;
    unsigned short* Whn1 = wb + 360448;

    hipMemsetAsync(degT, 0, (size_t)NN * 4 * sizeof(int), stream);
    place_bucket<<<(TT * EE + 255) / 256, 256, 0, stream>>>(edges, degT, rowsT);

    // work items: NN degP + 376832 weights + 1024 bias + NN*HH x + 128 zero = 6827984
    setup_convert<<<26672, 256, 0, stream>>>(msg_W, W0ih, W0hh, W1ih, W1hh,
                                             b0ih, b0hh, b1ih, b1hh, x,
                                             degT, degP, wb, biasP, xb, hbA, hbB, out);

    const int gblocks = (NN + 63) / 64;   // 782
    for (int s = 0; s < 6; ++s) {
        const int l = s / 3;
        const float* hcur  = (s % 2 == 0) ? out : hA;
        float*       hnext = (s % 2 == 0) ? hA : out;
        unsigned short* hbc = (s % 2 == 0) ? hbA : hbB;
        unsigned short* hbn = (s % 2 == 0) ? hbB : hbA;
        if (s == 5) hbn = nullptr;        // last step: bf16 h never consumed
        if (l == 0)
            step_kernel<0><<<gblocks, 512, 0, stream>>>(
                degP, rowsT, hbc, xb, Bmsg, msg_b, Wrz0, Wxn0, Whn0,
                biasP, hcur, hnext, hbn);
        else
            step_kernel<1><<<gblocks, 512, 0, stream>>>(
                degP, rowsT, hbc, xb, Bmsg + 65536, msg_b + 512, Wrz1, Wxn1, Whn1,
                biasP + 512, hcur, hnext, hbn);
    }
    // s=5 (odd) writes hnext=out — final h lands in d_out.
}